// Round 3
// baseline (3161.665 us; speedup 1.0000x reference)
//
#include <hip/hip_runtime.h>
#include <math.h>

#define NN 10000
#define NFEAT 512
#define NHID 256
#define NCLASS 40
#define NLAYERS 8
#define MAXDEG 96
#define NE 104          // 1 self + up to 96 edges, padded to multiple of 8
#define NTILES 625      // 16-row tiles; mega grid == NTILES (co-residency proven)

typedef __attribute__((ext_vector_type(8))) short bf16x8;
typedef __attribute__((ext_vector_type(4))) float floatx4;
typedef __attribute__((ext_vector_type(2))) float floatx2;
typedef __attribute__((ext_vector_type(4))) unsigned short ushort4v;

__device__ __forceinline__ unsigned short f2bf(float f) {
    union { float f; unsigned int u; } v; v.f = f;
    unsigned int r = v.u + 0x7fffu + ((v.u >> 16) & 1u);  // RNE
    return (unsigned short)(r >> 16);
}
__device__ __forceinline__ float bf2f(unsigned short h) {
    union { unsigned int u; float f; } v; v.u = ((unsigned int)h) << 16;
    return v.f;
}
__device__ __forceinline__ unsigned char f2fp8(float f) {
    return (unsigned char)(__builtin_amdgcn_cvt_pk_fp8_f32(f, f, 0, false) & 0xFF);
}

// ---------------------------------------------------------------------------
// software grid barrier.  Deadlock-proof: bounded spin (~0.3s) guarantees
// kernel termination even if visibility assumptions fail (=> finite absmax
// diagnostic instead of a wedged container).  Release/acquire agent fences
// handle cross-XCD L2 non-coherence.
// ---------------------------------------------------------------------------
__device__ __forceinline__ void grid_barrier(unsigned int* bar, unsigned int nblk) {
    __syncthreads();          // all block work done
    __threadfence();          // release: flush dirty L2 lines to LLC
    if (threadIdx.x == 0) {
        __hip_atomic_fetch_add(bar, 1u, __ATOMIC_RELEASE, __HIP_MEMORY_SCOPE_AGENT);
        int spins = 0;
        while (__hip_atomic_load(bar, __ATOMIC_ACQUIRE, __HIP_MEMORY_SCOPE_AGENT) < nblk
               && spins < (1 << 22)) {
            __builtin_amdgcn_s_sleep(2);
            ++spins;
        }
    }
    __syncthreads();
    __threadfence();          // acquire: invalidate stale lines before reading peers
}

// ---------------------------------------------------------------------------
// build_graph: one block per row; one pass over the 400MB dense adjacency.
// ---------------------------------------------------------------------------
__global__ __launch_bounds__(256) void build_graph(const float* __restrict__ adj,
                                                   int* __restrict__ cnt,
                                                   int* __restrict__ ell,
                                                   float* __restrict__ dinv) {
    int i = blockIdx.x;
    __shared__ int scnt;
    if (threadIdx.x == 0) scnt = 0;
    __syncthreads();
    const float4* row = (const float4*)(adj + (size_t)i * NN);
    const int nv = NN / 4;  // 2500
    int* erow = ell + (size_t)i * MAXDEG;
    for (int f = threadIdx.x; f < nv; f += 256) {
        float4 v = row[f];
        if (v.x != 0.0f) { int s = atomicAdd(&scnt, 1); if (s < MAXDEG) erow[s] = 4*f + 0; }
        if (v.y != 0.0f) { int s = atomicAdd(&scnt, 1); if (s < MAXDEG) erow[s] = 4*f + 1; }
        if (v.z != 0.0f) { int s = atomicAdd(&scnt, 1); if (s < MAXDEG) erow[s] = 4*f + 2; }
        if (v.w != 0.0f) { int s = atomicAdd(&scnt, 1); if (s < MAXDEG) erow[s] = 4*f + 3; }
    }
    __syncthreads();
    if (threadIdx.x == 0) {
        int c = scnt;
        cnt[i] = (c < MAXDEG) ? c : MAXDEG;
        dinv[i] = rsqrtf(1.0f + (float)c);
    }
}

// ---------------------------------------------------------------------------
// convert x -> bf16 (4 elements / thread)
// ---------------------------------------------------------------------------
__global__ __launch_bounds__(256) void convert_x(const float* __restrict__ x,
                                                 unsigned short* __restrict__ xb) {
    int idx = blockIdx.x * 256 + threadIdx.x;
    float4 v = ((const float4*)x)[idx];
    ushort4v o;
    o.x = f2bf(v.x); o.y = f2bf(v.y); o.z = f2bf(v.z); o.w = f2bf(v.w);
    ((ushort4v*)xb)[idx] = o;
}

// ---------------------------------------------------------------------------
// prep_weights: w0t/Mt transposes (+ residual fold) and zero barrier counters
// (re-zeroed on every graph replay; stream-ordered before gcn_mega).
// ---------------------------------------------------------------------------
__global__ __launch_bounds__(256) void prep_weights(const float* __restrict__ w0,
                                                    const float* __restrict__ cw,
                                                    unsigned short* __restrict__ w0t,
                                                    unsigned short* __restrict__ Mt,
                                                    unsigned int* __restrict__ bar) {
    int idx = blockIdx.x * 256 + threadIdx.x;
    if (idx < 16) bar[idx] = 0;
    if (idx < 131072) {
        int n = idx >> 9, k = idx & 511;
        w0t[idx] = f2bf(w0[(size_t)k * 256 + n]);
    } else {
        int j = idx - 131072;
        int l = j >> 16;
        int r = j & 65535;
        int n = r >> 8, k = r & 255;
        float theta = logf(0.5f / (float)(l + 1) + 1.0f);
        float v = theta * cw[(size_t)l * 65536 + (size_t)k * 256 + n];
        if (k == n) v += 1.0f - theta;
        Mt[j] = f2bf(v);
    }
}

// ---------------------------------------------------------------------------
// gemm0: h0 = relu(x @ w0 + b0); writes bf16 h0b AND fp8 h08 (convert fused,
// numerically identical: fp8 encoded from the rounded bf16 value).
// ---------------------------------------------------------------------------
__global__ __launch_bounds__(512, 4) void gemm0_mfma(const unsigned short* __restrict__ xb,
                                                     const unsigned short* __restrict__ w0t,
                                                     const float* __restrict__ b0,
                                                     unsigned short* __restrict__ h0b,
                                                     unsigned char* __restrict__ h8o) {
    int t = threadIdx.x, wv = t >> 6, lane = t & 63;
    int lrow = lane & 15, quad = lane >> 4;
    int r0 = blockIdx.x * 16;

    bf16x8 a[16];
    const unsigned short* arow = xb + (size_t)(r0 + lrow) * NFEAT + quad * 8;
    #pragma unroll
    for (int f = 0; f < 16; ++f)
        a[f] = *(const bf16x8*)(arow + f * 32);

    #pragma unroll 1
    for (int n = 0; n < 2; ++n) {
        int nt = wv * 2 + n;
        floatx4 acc = {0.f, 0.f, 0.f, 0.f};
        const unsigned short* wrow = w0t + (size_t)(nt * 16 + lrow) * NFEAT + quad * 8;
        #pragma unroll
        for (int f = 0; f < 16; ++f) {
            bf16x8 b = *(const bf16x8*)(wrow + f * 32);
            acc = __builtin_amdgcn_mfma_f32_16x16x32_bf16(a[f], b, acc, 0, 0, 0);
        }
        int col = nt * 16 + lrow;
        float bias = b0[col];
        #pragma unroll
        for (int r = 0; r < 4; ++r) {
            int row = r0 + quad * 4 + r;
            unsigned short bv = f2bf(fmaxf(acc[r] + bias, 0.f));
            h0b[(size_t)row * NHID + col] = bv;
            h8o[(size_t)row * NHID + col] = f2fp8(bf2f(bv));
        }
    }
}

// ---------------------------------------------------------------------------
// gcn_mega: all 8 layers + log_softmax in ONE launch, grid == NTILES (625),
// one 16-row tile per block, software grid barrier between layers.
//   __launch_bounds__(512,6) -> <=85 VGPR -> >=3 blocks/CU -> 768 slots >= 625
//   => co-residency guaranteed; bounded spin => termination guaranteed.
// Edge metadata staged ONCE in LDS (slot 0 = self, scale dinv[i]; pads 0);
// h0 residual row pinned in registers across all layers.
// ---------------------------------------------------------------------------
__global__ __launch_bounds__(512, 6) void gcn_mega(const unsigned int* __restrict__ h8in,
                                                   const unsigned short* __restrict__ h0b,
                                                   const float* __restrict__ dinv,
                                                   const int* __restrict__ cnt,
                                                   const int* __restrict__ ell,
                                                   const unsigned short* __restrict__ Mt,
                                                   const float* __restrict__ w1,
                                                   const float* __restrict__ b1,
                                                   unsigned int* __restrict__ bufA,
                                                   unsigned int* __restrict__ bufB,
                                                   float* __restrict__ out,
                                                   unsigned int* __restrict__ bar) {
    __shared__ unsigned short supb[16][264];
    __shared__ float hs[16 * 264];
    __shared__ int2  ed[16][NE];     // (neighbor j, scale bits); slot 0 = self
    __shared__ float s_di[16];
    __shared__ int   s_dm[16];

    int t = threadIdx.x;
    int wv = __builtin_amdgcn_readfirstlane(t >> 6);
    int lane = t & 63;
    int lrow = lane & 15, quad = lane >> 4;
    int r0 = blockIdx.x * 16;
    int lr0 = wv * 2, lr1 = lr0 + 1;
    int i0 = r0 + lr0, i1 = r0 + lr1;

    // ---- init: edge metadata -> LDS (once); h0 rows -> registers ----
    ushort4v h0v0, h0v1;
    {
        int c0 = cnt[i0], c1 = cnt[i1];
        float d0 = dinv[i0], d1 = dinv[i1];
        if (lane == 0) {
            s_di[lr0] = d0; s_dm[lr0] = (c0 + 8) & ~7;   // +1 self slot, pad to 8
            s_di[lr1] = d1; s_dm[lr1] = (c1 + 8) & ~7;
        }
        for (int e = lane; e < NE; e += 64) {
            int j = 0; float s = 0.0f;
            if (e == 0)       { j = i0; s = d0; }
            else if (e <= c0) { j = ell[(size_t)i0 * MAXDEG + e - 1]; s = dinv[j]; }
            int2 v; v.x = j; v.y = __float_as_int(s);
            ed[lr0][e] = v;
            j = 0; s = 0.0f;
            if (e == 0)       { j = i1; s = d1; }
            else if (e <= c1) { j = ell[(size_t)i1 * MAXDEG + e - 1]; s = dinv[j]; }
            v.x = j; v.y = __float_as_int(s);
            ed[lr1][e] = v;
        }
        h0v0 = ((const ushort4v*)h0b)[(size_t)i0 * 64 + lane];
        h0v1 = ((const ushort4v*)h0b)[(size_t)i1 * 64 + lane];
    }
    __syncthreads();

    const unsigned int* hc = h8in;

    #pragma unroll 1
    for (int l = 0; l < NLAYERS; ++l) {
        // ---- phase 1: fp8 gather + mix, two rows interleaved ----
        float di0 = s_di[lr0], di1 = s_di[lr1];
        int dA = s_dm[lr0], dB = s_dm[lr1];
        int dm = dA > dB ? dA : dB;                 // pads are scale-0, safe
        float4 a0 = {0.f, 0.f, 0.f, 0.f};
        float4 a1 = {0.f, 0.f, 0.f, 0.f};
        #pragma unroll 1
        for (int e0 = 0; e0 < dm; e0 += 8) {
            unsigned int x0[8], x1[8];
            float sc0[8], sc1[8];
            #pragma unroll
            for (int u = 0; u < 8; ++u) {
                int2 p = ed[lr0][e0 + u];           // broadcast LDS read
                int2 q = ed[lr1][e0 + u];
                int pj = __builtin_amdgcn_readfirstlane(p.x);   // uniform -> SGPR
                int qj = __builtin_amdgcn_readfirstlane(q.x);
                sc0[u] = __int_as_float(__builtin_amdgcn_readfirstlane(p.y));
                sc1[u] = __int_as_float(__builtin_amdgcn_readfirstlane(q.y));
                x0[u] = hc[(size_t)pj * 64 + lane];
                x1[u] = hc[(size_t)qj * 64 + lane];
            }
            #pragma unroll
            for (int u = 0; u < 8; ++u) {
                floatx2 lo = __builtin_amdgcn_cvt_pk_f32_fp8(x0[u], false);
                floatx2 hi = __builtin_amdgcn_cvt_pk_f32_fp8(x0[u], true);
                a0.x = fmaf(sc0[u], lo.x, a0.x);
                a0.y = fmaf(sc0[u], lo.y, a0.y);
                a0.z = fmaf(sc0[u], hi.x, a0.z);
                a0.w = fmaf(sc0[u], hi.y, a0.w);
                lo = __builtin_amdgcn_cvt_pk_f32_fp8(x1[u], false);
                hi = __builtin_amdgcn_cvt_pk_f32_fp8(x1[u], true);
                a1.x = fmaf(sc1[u], lo.x, a1.x);
                a1.y = fmaf(sc1[u], lo.y, a1.y);
                a1.z = fmaf(sc1[u], hi.x, a1.z);
                a1.w = fmaf(sc1[u], hi.y, a1.w);
            }
        }
        ushort4v ob;
        ob.x = f2bf(0.9f * (di0 * a0.x) + 0.1f * bf2f(h0v0.x));
        ob.y = f2bf(0.9f * (di0 * a0.y) + 0.1f * bf2f(h0v0.y));
        ob.z = f2bf(0.9f * (di0 * a0.z) + 0.1f * bf2f(h0v0.z));
        ob.w = f2bf(0.9f * (di0 * a0.w) + 0.1f * bf2f(h0v0.w));
        *(ushort4v*)&supb[lr0][4 * lane] = ob;
        ob.x = f2bf(0.9f * (di1 * a1.x) + 0.1f * bf2f(h0v1.x));
        ob.y = f2bf(0.9f * (di1 * a1.y) + 0.1f * bf2f(h0v1.y));
        ob.z = f2bf(0.9f * (di1 * a1.z) + 0.1f * bf2f(h0v1.z));
        ob.w = f2bf(0.9f * (di1 * a1.w) + 0.1f * bf2f(h0v1.w));
        *(ushort4v*)&supb[lr1][4 * lane] = ob;
        __syncthreads();

        // ---- phase 2: MFMA GEMM, residual folded into Mt ----
        const unsigned short* Ml = Mt + (size_t)l * NHID * NHID;
        bool last = (l == NLAYERS - 1);
        unsigned char* ho = (unsigned char*)((l & 1) ? bufB : bufA);
        bf16x8 a[8];
        #pragma unroll
        for (int f = 0; f < 8; ++f)
            a[f] = *(const bf16x8*)&supb[lrow][quad * 8 + f * 32];

        #pragma unroll 1
        for (int n = 0; n < 2; ++n) {
            int nt = wv * 2 + n;
            floatx4 acc = {0.f, 0.f, 0.f, 0.f};
            const unsigned short* wrow = Ml + (size_t)(nt * 16 + lrow) * NHID + quad * 8;
            #pragma unroll
            for (int f = 0; f < 8; ++f) {
                bf16x8 b = *(const bf16x8*)(wrow + f * 32);
                acc = __builtin_amdgcn_mfma_f32_16x16x32_bf16(a[f], b, acc, 0, 0, 0);
            }
            int col = nt * 16 + lrow;
            #pragma unroll
            for (int r = 0; r < 4; ++r) {
                int lr2 = quad * 4 + r;
                float o = fmaxf(acc[r], 0.f);
                if (last) hs[lr2 * 264 + col] = o;
                else      ho[(size_t)(r0 + lr2) * NHID + col] = f2fp8(o);
            }
        }
        if (!last) {
            grid_barrier(bar + l, NTILES);   // also orders supb reuse next layer
            hc = (const unsigned int*)ho;
        }
    }

    // ---- phase 3: logits + log_softmax, in-block ----
    __syncthreads();
    #pragma unroll 1
    for (int rr = 0; rr < 2; ++rr) {
        int lr = wv * 2 + rr;
        const float* hr = hs + lr * 264;
        float logit = -1e30f;
        if (lane < NCLASS) {
            float acc = b1[lane];
            #pragma unroll 8
            for (int k = 0; k < NHID; ++k)
                acc = fmaf(hr[k], w1[k * NCLASS + lane], acc);
            logit = acc;
        }
        float m = logit;
        #pragma unroll
        for (int off = 32; off > 0; off >>= 1)
            m = fmaxf(m, __shfl_xor(m, off, 64));
        float e = (lane < NCLASS) ? expf(logit - m) : 0.0f;
        float ssum = e;
        #pragma unroll
        for (int off = 32; off > 0; off >>= 1)
            ssum += __shfl_xor(ssum, off, 64);
        float lse = m + logf(ssum);
        if (lane < NCLASS)
            out[(size_t)(r0 + lr) * NCLASS + lane] = logit - lse;
    }
}

// ---------------------------------------------------------------------------
extern "C" void kernel_launch(void* const* d_in, const int* in_sizes, int n_in,
                              void* d_out, int out_size, void* d_ws, size_t ws_size,
                              hipStream_t stream) {
    const float* x      = (const float*)d_in[0];
    const float* adj    = (const float*)d_in[1];
    const float* w0     = (const float*)d_in[2];
    const float* b0     = (const float*)d_in[3];
    const float* conv_w = (const float*)d_in[4];
    const float* w1     = (const float*)d_in[5];
    const float* b1     = (const float*)d_in[6];
    float* out = (float*)d_out;

    char* ws = (char*)d_ws;
    size_t off = 0;
    auto alloc = [&](size_t bytes) -> void* {
        void* p = ws + off;
        off = (off + bytes + 255) & ~(size_t)255;
        return p;
    };
    float*          dinv  = (float*)alloc((size_t)NN * 4);
    int*            cnt   = (int*)  alloc((size_t)NN * 4);
    int*            ell   = (int*)  alloc((size_t)NN * MAXDEG * 4);
    unsigned short* xb    = (unsigned short*)alloc((size_t)NN * NFEAT * 2);
    unsigned short* w0t   = (unsigned short*)alloc((size_t)NFEAT * NHID * 2);
    unsigned short* Mt    = (unsigned short*)alloc((size_t)NLAYERS * NHID * NHID * 2);
    unsigned short* h0b   = (unsigned short*)alloc((size_t)NN * NHID * 2);
    unsigned int*   h08   = (unsigned int*)alloc((size_t)NN * NHID);
    unsigned int*   hP8   = (unsigned int*)alloc((size_t)NN * NHID);
    unsigned int*   hQ8   = (unsigned int*)alloc((size_t)NN * NHID);
    unsigned int*   bar   = (unsigned int*)alloc(16 * 4);

    build_graph<<<NN, 256, 0, stream>>>(adj, cnt, ell, dinv);
    convert_x<<<(NN * NFEAT / 4) / 256, 256, 0, stream>>>(x, xb);
    prep_weights<<<(131072 + NLAYERS * NHID * NHID) / 256, 256, 0, stream>>>(w0, conv_w, w0t, Mt, bar);
    gemm0_mfma<<<NN / 16, 512, 0, stream>>>(xb, w0t, b0, h0b, (unsigned char*)h08);

    gcn_mega<<<NTILES, 512, 0, stream>>>(h08, h0b, dinv, cnt, ell, Mt, w1, b1,
                                         hP8, hQ8, out, bar);
}

// Round 4
// 2506.239 us; speedup vs baseline: 1.2615x; 1.2615x over previous
//
#include <hip/hip_runtime.h>
#include <math.h>

#define NN 10000
#define NFEAT 512
#define NHID 256
#define NCLASS 40
#define NLAYERS 8
#define MAXDEG 96
#define NE 104          // 1 self + up to 96 edges, padded to multiple of 8
#define NTILES 625      // 16-row tiles; mega grid == NTILES (co-residency proven R3)

typedef __attribute__((ext_vector_type(8))) short bf16x8;
typedef __attribute__((ext_vector_type(4))) float floatx4;
typedef __attribute__((ext_vector_type(2))) float floatx2;
typedef __attribute__((ext_vector_type(4))) unsigned short ushort4v;

__device__ __forceinline__ unsigned short f2bf(float f) {
    union { float f; unsigned int u; } v; v.f = f;
    unsigned int r = v.u + 0x7fffu + ((v.u >> 16) & 1u);  // RNE
    return (unsigned short)(r >> 16);
}
__device__ __forceinline__ float bf2f(unsigned short h) {
    union { unsigned int u; float f; } v; v.u = ((unsigned int)h) << 16;
    return v.f;
}
__device__ __forceinline__ unsigned char f2fp8(float f) {
    return (unsigned char)(__builtin_amdgcn_cvt_pk_fp8_f32(f, f, 0, false) & 0xFF);
}

// ---------------------------------------------------------------------------
// software grid barrier, RELAXED-poll edition.
//   R3 post-mortem: ACQUIRE-ordered polls emit buffer_inv (full L2 invalidate)
//   EVERY iteration -> 625 pollers wiped each XCD L2 ~100x/us while straggler
//   blocks were still computing -> cache-less gathers -> 2560us. Fix:
//   - release: ONE __threadfence() (waitcnt+wbl2), then RELAXED fetch_add
//   - poll:    RELAXED agent atomic load (scope forces coherence-point read,
//              sees updates; relaxed ordering emits NO buffer_inv)
//   - exit:    __syncthreads + ONE acquire __threadfence (single L2 inv/layer)
//   Bounded spin (2^18) guarantees termination even if assumptions fail.
// ---------------------------------------------------------------------------
__device__ __forceinline__ void grid_barrier(unsigned int* bar, unsigned int nblk) {
    __syncthreads();          // all block work done
    __threadfence();          // release once: vmcnt drain + L2 writeback
    if (threadIdx.x == 0) {
        __hip_atomic_fetch_add(bar, 1u, __ATOMIC_RELAXED, __HIP_MEMORY_SCOPE_AGENT);
        int spins = 0;
        while (__hip_atomic_load(bar, __ATOMIC_RELAXED, __HIP_MEMORY_SCOPE_AGENT) < nblk
               && spins < (1 << 18)) {
            __builtin_amdgcn_s_sleep(8);   // ~512 cyc between polls
            ++spins;
        }
    }
    __syncthreads();
    __threadfence();          // acquire once: invalidate stale lines, then read peers
}

// ---------------------------------------------------------------------------
// build_graph: one block per row; one pass over the 400MB dense adjacency.
// ---------------------------------------------------------------------------
__global__ __launch_bounds__(256) void build_graph(const float* __restrict__ adj,
                                                   int* __restrict__ cnt,
                                                   int* __restrict__ ell,
                                                   float* __restrict__ dinv) {
    int i = blockIdx.x;
    __shared__ int scnt;
    if (threadIdx.x == 0) scnt = 0;
    __syncthreads();
    const float4* row = (const float4*)(adj + (size_t)i * NN);
    const int nv = NN / 4;  // 2500
    int* erow = ell + (size_t)i * MAXDEG;
    for (int f = threadIdx.x; f < nv; f += 256) {
        float4 v = row[f];
        if (v.x != 0.0f) { int s = atomicAdd(&scnt, 1); if (s < MAXDEG) erow[s] = 4*f + 0; }
        if (v.y != 0.0f) { int s = atomicAdd(&scnt, 1); if (s < MAXDEG) erow[s] = 4*f + 1; }
        if (v.z != 0.0f) { int s = atomicAdd(&scnt, 1); if (s < MAXDEG) erow[s] = 4*f + 2; }
        if (v.w != 0.0f) { int s = atomicAdd(&scnt, 1); if (s < MAXDEG) erow[s] = 4*f + 3; }
    }
    __syncthreads();
    if (threadIdx.x == 0) {
        int c = scnt;
        cnt[i] = (c < MAXDEG) ? c : MAXDEG;
        dinv[i] = rsqrtf(1.0f + (float)c);
    }
}

// ---------------------------------------------------------------------------
// convert x -> bf16 (4 elements / thread)
// ---------------------------------------------------------------------------
__global__ __launch_bounds__(256) void convert_x(const float* __restrict__ x,
                                                 unsigned short* __restrict__ xb) {
    int idx = blockIdx.x * 256 + threadIdx.x;
    float4 v = ((const float4*)x)[idx];
    ushort4v o;
    o.x = f2bf(v.x); o.y = f2bf(v.y); o.z = f2bf(v.z); o.w = f2bf(v.w);
    ((ushort4v*)xb)[idx] = o;
}

// ---------------------------------------------------------------------------
// prep_weights: w0t/Mt transposes (+ residual fold) and zero barrier counters
// (re-zeroed on every graph replay; stream-ordered before gcn_mega).
// ---------------------------------------------------------------------------
__global__ __launch_bounds__(256) void prep_weights(const float* __restrict__ w0,
                                                    const float* __restrict__ cw,
                                                    unsigned short* __restrict__ w0t,
                                                    unsigned short* __restrict__ Mt,
                                                    unsigned int* __restrict__ bar) {
    int idx = blockIdx.x * 256 + threadIdx.x;
    if (idx < 16) bar[idx] = 0;
    if (idx < 131072) {
        int n = idx >> 9, k = idx & 511;
        w0t[idx] = f2bf(w0[(size_t)k * 256 + n]);
    } else {
        int j = idx - 131072;
        int l = j >> 16;
        int r = j & 65535;
        int n = r >> 8, k = r & 255;
        float theta = logf(0.5f / (float)(l + 1) + 1.0f);
        float v = theta * cw[(size_t)l * 65536 + (size_t)k * 256 + n];
        if (k == n) v += 1.0f - theta;
        Mt[j] = f2bf(v);
    }
}

// ---------------------------------------------------------------------------
// gemm0: h0 = relu(x @ w0 + b0); writes bf16 h0b AND fp8 h08 (convert fused,
// numerically identical: fp8 encoded from the rounded bf16 value).
// ---------------------------------------------------------------------------
__global__ __launch_bounds__(512, 4) void gemm0_mfma(const unsigned short* __restrict__ xb,
                                                     const unsigned short* __restrict__ w0t,
                                                     const float* __restrict__ b0,
                                                     unsigned short* __restrict__ h0b,
                                                     unsigned char* __restrict__ h8o) {
    int t = threadIdx.x, wv = t >> 6, lane = t & 63;
    int lrow = lane & 15, quad = lane >> 4;
    int r0 = blockIdx.x * 16;

    bf16x8 a[16];
    const unsigned short* arow = xb + (size_t)(r0 + lrow) * NFEAT + quad * 8;
    #pragma unroll
    for (int f = 0; f < 16; ++f)
        a[f] = *(const bf16x8*)(arow + f * 32);

    #pragma unroll 1
    for (int n = 0; n < 2; ++n) {
        int nt = wv * 2 + n;
        floatx4 acc = {0.f, 0.f, 0.f, 0.f};
        const unsigned short* wrow = w0t + (size_t)(nt * 16 + lrow) * NFEAT + quad * 8;
        #pragma unroll
        for (int f = 0; f < 16; ++f) {
            bf16x8 b = *(const bf16x8*)(wrow + f * 32);
            acc = __builtin_amdgcn_mfma_f32_16x16x32_bf16(a[f], b, acc, 0, 0, 0);
        }
        int col = nt * 16 + lrow;
        float bias = b0[col];
        #pragma unroll
        for (int r = 0; r < 4; ++r) {
            int row = r0 + quad * 4 + r;
            unsigned short bv = f2bf(fmaxf(acc[r] + bias, 0.f));
            h0b[(size_t)row * NHID + col] = bv;
            h8o[(size_t)row * NHID + col] = f2fp8(bf2f(bv));
        }
    }
}

// ---------------------------------------------------------------------------
// gcn_mega: all 8 layers + log_softmax in ONE launch, grid == NTILES (625),
// one 16-row tile per block, relaxed-poll grid barrier between layers.
//   R3 proved: co-residency holds (occupancy 60%), numerics exact.
// Edge metadata staged ONCE in LDS (slot 0 = self, scale dinv[i]; pads 0);
// h0 residual row pinned in registers across all layers.
// ---------------------------------------------------------------------------
__global__ __launch_bounds__(512, 6) void gcn_mega(const unsigned int* __restrict__ h8in,
                                                   const unsigned short* __restrict__ h0b,
                                                   const float* __restrict__ dinv,
                                                   const int* __restrict__ cnt,
                                                   const int* __restrict__ ell,
                                                   const unsigned short* __restrict__ Mt,
                                                   const float* __restrict__ w1,
                                                   const float* __restrict__ b1,
                                                   unsigned int* __restrict__ bufA,
                                                   unsigned int* __restrict__ bufB,
                                                   float* __restrict__ out,
                                                   unsigned int* __restrict__ bar) {
    __shared__ unsigned short supb[16][264];
    __shared__ float hs[16 * 264];
    __shared__ int2  ed[16][NE];     // (neighbor j, scale bits); slot 0 = self
    __shared__ float s_di[16];
    __shared__ int   s_dm[16];

    int t = threadIdx.x;
    int wv = __builtin_amdgcn_readfirstlane(t >> 6);
    int lane = t & 63;
    int lrow = lane & 15, quad = lane >> 4;
    int r0 = blockIdx.x * 16;
    int lr0 = wv * 2, lr1 = lr0 + 1;
    int i0 = r0 + lr0, i1 = r0 + lr1;

    // ---- init: edge metadata -> LDS (once); h0 rows -> registers ----
    ushort4v h0v0, h0v1;
    {
        int c0 = cnt[i0], c1 = cnt[i1];
        float d0 = dinv[i0], d1 = dinv[i1];
        if (lane == 0) {
            s_di[lr0] = d0; s_dm[lr0] = (c0 + 8) & ~7;   // +1 self slot, pad to 8
            s_di[lr1] = d1; s_dm[lr1] = (c1 + 8) & ~7;
        }
        for (int e = lane; e < NE; e += 64) {
            int j = 0; float s = 0.0f;
            if (e == 0)       { j = i0; s = d0; }
            else if (e <= c0) { j = ell[(size_t)i0 * MAXDEG + e - 1]; s = dinv[j]; }
            int2 v; v.x = j; v.y = __float_as_int(s);
            ed[lr0][e] = v;
            j = 0; s = 0.0f;
            if (e == 0)       { j = i1; s = d1; }
            else if (e <= c1) { j = ell[(size_t)i1 * MAXDEG + e - 1]; s = dinv[j]; }
            v.x = j; v.y = __float_as_int(s);
            ed[lr1][e] = v;
        }
        h0v0 = ((const ushort4v*)h0b)[(size_t)i0 * 64 + lane];
        h0v1 = ((const ushort4v*)h0b)[(size_t)i1 * 64 + lane];
    }
    __syncthreads();

    const unsigned int* hc = h8in;

    #pragma unroll 1
    for (int l = 0; l < NLAYERS; ++l) {
        // ---- phase 1: fp8 gather + mix, two rows interleaved ----
        float di0 = s_di[lr0], di1 = s_di[lr1];
        int dA = s_dm[lr0], dB = s_dm[lr1];
        int dm = dA > dB ? dA : dB;                 // pads are scale-0, safe
        float4 a0 = {0.f, 0.f, 0.f, 0.f};
        float4 a1 = {0.f, 0.f, 0.f, 0.f};
        #pragma unroll 1
        for (int e0 = 0; e0 < dm; e0 += 8) {
            unsigned int x0[8], x1[8];
            float sc0[8], sc1[8];
            #pragma unroll
            for (int u = 0; u < 8; ++u) {
                int2 p = ed[lr0][e0 + u];           // broadcast LDS read
                int2 q = ed[lr1][e0 + u];
                int pj = __builtin_amdgcn_readfirstlane(p.x);   // uniform -> SGPR
                int qj = __builtin_amdgcn_readfirstlane(q.x);
                sc0[u] = __int_as_float(__builtin_amdgcn_readfirstlane(p.y));
                sc1[u] = __int_as_float(__builtin_amdgcn_readfirstlane(q.y));
                x0[u] = hc[(size_t)pj * 64 + lane];
                x1[u] = hc[(size_t)qj * 64 + lane];
            }
            #pragma unroll
            for (int u = 0; u < 8; ++u) {
                floatx2 lo = __builtin_amdgcn_cvt_pk_f32_fp8(x0[u], false);
                floatx2 hi = __builtin_amdgcn_cvt_pk_f32_fp8(x0[u], true);
                a0.x = fmaf(sc0[u], lo.x, a0.x);
                a0.y = fmaf(sc0[u], lo.y, a0.y);
                a0.z = fmaf(sc0[u], hi.x, a0.z);
                a0.w = fmaf(sc0[u], hi.y, a0.w);
                lo = __builtin_amdgcn_cvt_pk_f32_fp8(x1[u], false);
                hi = __builtin_amdgcn_cvt_pk_f32_fp8(x1[u], true);
                a1.x = fmaf(sc1[u], lo.x, a1.x);
                a1.y = fmaf(sc1[u], lo.y, a1.y);
                a1.z = fmaf(sc1[u], hi.x, a1.z);
                a1.w = fmaf(sc1[u], hi.y, a1.w);
            }
        }
        ushort4v ob;
        ob.x = f2bf(0.9f * (di0 * a0.x) + 0.1f * bf2f(h0v0.x));
        ob.y = f2bf(0.9f * (di0 * a0.y) + 0.1f * bf2f(h0v0.y));
        ob.z = f2bf(0.9f * (di0 * a0.z) + 0.1f * bf2f(h0v0.z));
        ob.w = f2bf(0.9f * (di0 * a0.w) + 0.1f * bf2f(h0v0.w));
        *(ushort4v*)&supb[lr0][4 * lane] = ob;
        ob.x = f2bf(0.9f * (di1 * a1.x) + 0.1f * bf2f(h0v1.x));
        ob.y = f2bf(0.9f * (di1 * a1.y) + 0.1f * bf2f(h0v1.y));
        ob.z = f2bf(0.9f * (di1 * a1.z) + 0.1f * bf2f(h0v1.z));
        ob.w = f2bf(0.9f * (di1 * a1.w) + 0.1f * bf2f(h0v1.w));
        *(ushort4v*)&supb[lr1][4 * lane] = ob;
        __syncthreads();

        // ---- phase 2: MFMA GEMM, residual folded into Mt ----
        const unsigned short* Ml = Mt + (size_t)l * NHID * NHID;
        bool last = (l == NLAYERS - 1);
        unsigned char* ho = (unsigned char*)((l & 1) ? bufB : bufA);
        bf16x8 a[8];
        #pragma unroll
        for (int f = 0; f < 8; ++f)
            a[f] = *(const bf16x8*)&supb[lrow][quad * 8 + f * 32];

        #pragma unroll 1
        for (int n = 0; n < 2; ++n) {
            int nt = wv * 2 + n;
            floatx4 acc = {0.f, 0.f, 0.f, 0.f};
            const unsigned short* wrow = Ml + (size_t)(nt * 16 + lrow) * NHID + quad * 8;
            #pragma unroll
            for (int f = 0; f < 8; ++f) {
                bf16x8 b = *(const bf16x8*)(wrow + f * 32);
                acc = __builtin_amdgcn_mfma_f32_16x16x32_bf16(a[f], b, acc, 0, 0, 0);
            }
            int col = nt * 16 + lrow;
            #pragma unroll
            for (int r = 0; r < 4; ++r) {
                int lr2 = quad * 4 + r;
                float o = fmaxf(acc[r], 0.f);
                if (last) hs[lr2 * 264 + col] = o;
                else      ho[(size_t)(r0 + lr2) * NHID + col] = f2fp8(o);
            }
        }
        if (!last) {
            grid_barrier(bar + l, NTILES);   // also orders supb reuse next layer
            hc = (const unsigned int*)ho;
        }
    }

    // ---- phase 3: logits + log_softmax, in-block ----
    __syncthreads();
    #pragma unroll 1
    for (int rr = 0; rr < 2; ++rr) {
        int lr = wv * 2 + rr;
        const float* hr = hs + lr * 264;
        float logit = -1e30f;
        if (lane < NCLASS) {
            float acc = b1[lane];
            #pragma unroll 8
            for (int k = 0; k < NHID; ++k)
                acc = fmaf(hr[k], w1[k * NCLASS + lane], acc);
            logit = acc;
        }
        float m = logit;
        #pragma unroll
        for (int off = 32; off > 0; off >>= 1)
            m = fmaxf(m, __shfl_xor(m, off, 64));
        float e = (lane < NCLASS) ? expf(logit - m) : 0.0f;
        float ssum = e;
        #pragma unroll
        for (int off = 32; off > 0; off >>= 1)
            ssum += __shfl_xor(ssum, off, 64);
        float lse = m + logf(ssum);
        if (lane < NCLASS)
            out[(size_t)(r0 + lr) * NCLASS + lane] = logit - lse;
    }
}

// ---------------------------------------------------------------------------
extern "C" void kernel_launch(void* const* d_in, const int* in_sizes, int n_in,
                              void* d_out, int out_size, void* d_ws, size_t ws_size,
                              hipStream_t stream) {
    const float* x      = (const float*)d_in[0];
    const float* adj    = (const float*)d_in[1];
    const float* w0     = (const float*)d_in[2];
    const float* b0     = (const float*)d_in[3];
    const float* conv_w = (const float*)d_in[4];
    const float* w1     = (const float*)d_in[5];
    const float* b1     = (const float*)d_in[6];
    float* out = (float*)d_out;

    char* ws = (char*)d_ws;
    size_t off = 0;
    auto alloc = [&](size_t bytes) -> void* {
        void* p = ws + off;
        off = (off + bytes + 255) & ~(size_t)255;
        return p;
    };
    float*          dinv  = (float*)alloc((size_t)NN * 4);
    int*            cnt   = (int*)  alloc((size_t)NN * 4);
    int*            ell   = (int*)  alloc((size_t)NN * MAXDEG * 4);
    unsigned short* xb    = (unsigned short*)alloc((size_t)NN * NFEAT * 2);
    unsigned short* w0t   = (unsigned short*)alloc((size_t)NFEAT * NHID * 2);
    unsigned short* Mt    = (unsigned short*)alloc((size_t)NLAYERS * NHID * NHID * 2);
    unsigned short* h0b   = (unsigned short*)alloc((size_t)NN * NHID * 2);
    unsigned int*   h08   = (unsigned int*)alloc((size_t)NN * NHID);
    unsigned int*   hP8   = (unsigned int*)alloc((size_t)NN * NHID);
    unsigned int*   hQ8   = (unsigned int*)alloc((size_t)NN * NHID);
    unsigned int*   bar   = (unsigned int*)alloc(16 * 4);

    build_graph<<<NN, 256, 0, stream>>>(adj, cnt, ell, dinv);
    convert_x<<<(NN * NFEAT / 4) / 256, 256, 0, stream>>>(x, xb);
    prep_weights<<<(131072 + NLAYERS * NHID * NHID) / 256, 256, 0, stream>>>(w0, conv_w, w0t, Mt, bar);
    gemm0_mfma<<<NN / 16, 512, 0, stream>>>(xb, w0t, b0, h0b, (unsigned char*)h08);

    gcn_mega<<<NTILES, 512, 0, stream>>>(h08, h0b, dinv, cnt, ell, Mt, w1, b1,
                                         hP8, hQ8, out, bar);
}

// Round 5
// 852.038 us; speedup vs baseline: 3.7107x; 2.9415x over previous
//
#include <hip/hip_runtime.h>
#include <math.h>

#define NN 10000
#define NFEAT 512
#define NHID 256
#define NCLASS 40
#define NLAYERS 8
#define MAXDEG 96

typedef __attribute__((ext_vector_type(8))) short bf16x8;
typedef __attribute__((ext_vector_type(4))) float floatx4;
typedef __attribute__((ext_vector_type(2))) float floatx2;
typedef __attribute__((ext_vector_type(4))) unsigned short ushort4v;

__device__ __forceinline__ unsigned short f2bf(float f) {
    union { float f; unsigned int u; } v; v.f = f;
    unsigned int r = v.u + 0x7fffu + ((v.u >> 16) & 1u);  // RNE
    return (unsigned short)(r >> 16);
}
__device__ __forceinline__ float bf2f(unsigned short h) {
    union { unsigned int u; float f; } v; v.u = ((unsigned int)h) << 16;
    return v.f;
}
__device__ __forceinline__ unsigned char f2fp8(float f) {
    return (unsigned char)(__builtin_amdgcn_cvt_pk_fp8_f32(f, f, 0, false) & 0xFF);
}

// ---------------------------------------------------------------------------
// build_graph: one block per row; one pass over the 400MB dense adjacency.
// ---------------------------------------------------------------------------
__global__ __launch_bounds__(256) void build_graph(const float* __restrict__ adj,
                                                   int* __restrict__ cnt,
                                                   int* __restrict__ ell,
                                                   float* __restrict__ dinv) {
    int i = blockIdx.x;
    __shared__ int scnt;
    if (threadIdx.x == 0) scnt = 0;
    __syncthreads();
    const float4* row = (const float4*)(adj + (size_t)i * NN);
    const int nv = NN / 4;  // 2500
    int* erow = ell + (size_t)i * MAXDEG;
    for (int f = threadIdx.x; f < nv; f += 256) {
        float4 v = row[f];
        if (v.x != 0.0f) { int s = atomicAdd(&scnt, 1); if (s < MAXDEG) erow[s] = 4*f + 0; }
        if (v.y != 0.0f) { int s = atomicAdd(&scnt, 1); if (s < MAXDEG) erow[s] = 4*f + 1; }
        if (v.z != 0.0f) { int s = atomicAdd(&scnt, 1); if (s < MAXDEG) erow[s] = 4*f + 2; }
        if (v.w != 0.0f) { int s = atomicAdd(&scnt, 1); if (s < MAXDEG) erow[s] = 4*f + 3; }
    }
    __syncthreads();
    if (threadIdx.x == 0) {
        int c = scnt;
        cnt[i] = (c < MAXDEG) ? c : MAXDEG;
        dinv[i] = rsqrtf(1.0f + (float)c);
    }
}

// ---------------------------------------------------------------------------
// prep_ell: es[i][e] = (j, bits(dinv[j])) for e<deg, else (0, 0.0f).
// Packed int2 -> ONE scalar load per edge in the layer gather (was two).
// ---------------------------------------------------------------------------
__global__ __launch_bounds__(256) void prep_ell(const int* __restrict__ ell,
                                                const int* __restrict__ cnt,
                                                const float* __restrict__ dinv,
                                                int2* __restrict__ es) {
    int idx = blockIdx.x * 256 + threadIdx.x;   // 960000 total
    if (idx >= NN * MAXDEG) return;
    int i = idx / MAXDEG, e = idx % MAXDEG;
    int2 v; v.x = 0; v.y = 0;                    // pad: row 0, scale 0.0
    if (e < cnt[i]) {
        int j = ell[idx];
        v.x = j; v.y = __float_as_int(dinv[j]);
    }
    es[idx] = v;
}

// ---------------------------------------------------------------------------
// convert x -> bf16 (4 elements / thread)
// ---------------------------------------------------------------------------
__global__ __launch_bounds__(256) void convert_x(const float* __restrict__ x,
                                                 unsigned short* __restrict__ xb) {
    int idx = blockIdx.x * 256 + threadIdx.x;
    float4 v = ((const float4*)x)[idx];
    ushort4v o;
    o.x = f2bf(v.x); o.y = f2bf(v.y); o.z = f2bf(v.z); o.w = f2bf(v.w);
    ((ushort4v*)xb)[idx] = o;
}

// ---------------------------------------------------------------------------
// prep_weights:
//   w0t[n][k]  = bf16(w0[k][n])                                 (256x512)
//   Mt[l][n][k] = bf16(theta_l * cw[l][k][n] + (1-theta_l)*I)   (fold residual)
// ---------------------------------------------------------------------------
__global__ __launch_bounds__(256) void prep_weights(const float* __restrict__ w0,
                                                    const float* __restrict__ cw,
                                                    unsigned short* __restrict__ w0t,
                                                    unsigned short* __restrict__ Mt) {
    int idx = blockIdx.x * 256 + threadIdx.x;
    if (idx < 131072) {
        int n = idx >> 9, k = idx & 511;
        w0t[idx] = f2bf(w0[(size_t)k * 256 + n]);
    } else {
        int j = idx - 131072;
        int l = j >> 16;
        int r = j & 65535;
        int n = r >> 8, k = r & 255;
        float theta = logf(0.5f / (float)(l + 1) + 1.0f);
        float v = theta * cw[(size_t)l * 65536 + (size_t)k * 256 + n];
        if (k == n) v += 1.0f - theta;
        Mt[j] = f2bf(v);
    }
}

// ---------------------------------------------------------------------------
// gemm0: h0 = relu(x @ w0 + b0); writes bf16 h0b AND fp8 h08 (convert fused,
// numerically identical: fp8 encoded from the rounded bf16 value).
// ---------------------------------------------------------------------------
__global__ __launch_bounds__(512, 4) void gemm0_mfma(const unsigned short* __restrict__ xb,
                                                     const unsigned short* __restrict__ w0t,
                                                     const float* __restrict__ b0,
                                                     unsigned short* __restrict__ h0b,
                                                     unsigned char* __restrict__ h8o) {
    int t = threadIdx.x, wv = t >> 6, lane = t & 63;
    int lrow = lane & 15, quad = lane >> 4;
    int r0 = blockIdx.x * 16;

    bf16x8 a[16];
    const unsigned short* arow = xb + (size_t)(r0 + lrow) * NFEAT + quad * 8;
    #pragma unroll
    for (int f = 0; f < 16; ++f)
        a[f] = *(const bf16x8*)(arow + f * 32);

    #pragma unroll 1
    for (int n = 0; n < 2; ++n) {
        int nt = wv * 2 + n;
        floatx4 acc = {0.f, 0.f, 0.f, 0.f};
        const unsigned short* wrow = w0t + (size_t)(nt * 16 + lrow) * NFEAT + quad * 8;
        #pragma unroll
        for (int f = 0; f < 16; ++f) {
            bf16x8 b = *(const bf16x8*)(wrow + f * 32);
            acc = __builtin_amdgcn_mfma_f32_16x16x32_bf16(a[f], b, acc, 0, 0, 0);
        }
        int col = nt * 16 + lrow;
        float bias = b0[col];
        #pragma unroll
        for (int r = 0; r < 4; ++r) {
            int row = r0 + quad * 4 + r;
            unsigned short bv = f2bf(fmaxf(acc[r] + bias, 0.f));
            h0b[(size_t)row * NHID + col] = bv;
            h8o[(size_t)row * NHID + col] = f2fp8(bf2f(bv));
        }
    }
}

// ---------------------------------------------------------------------------
// gather pipeline helpers: array-reference args + full unroll -> registers.
// ---------------------------------------------------------------------------
__device__ __forceinline__ void load_group(const int2* __restrict__ e0r,
                                           const int2* __restrict__ e1r,
                                           const unsigned int* __restrict__ h8,
                                           int lane, int base,
                                           unsigned int (&x0)[8], unsigned int (&x1)[8],
                                           float (&s0)[8], float (&s1)[8]) {
    #pragma unroll
    for (int u = 0; u < 8; ++u) {
        int2 p = e0r[base + u];            // uniform -> s_load_dwordx2
        int2 q = e1r[base + u];
        s0[u] = __int_as_float(p.y);
        s1[u] = __int_as_float(q.y);
        x0[u] = h8[(size_t)p.x * 64 + lane];
        x1[u] = h8[(size_t)q.x * 64 + lane];
    }
}

__device__ __forceinline__ void proc_group(const unsigned int (&x0)[8],
                                           const unsigned int (&x1)[8],
                                           const float (&s0)[8], const float (&s1)[8],
                                           float4& a0, float4& a1) {
    #pragma unroll
    for (int u = 0; u < 8; ++u) {
        floatx2 lo = __builtin_amdgcn_cvt_pk_f32_fp8(x0[u], false);
        floatx2 hi = __builtin_amdgcn_cvt_pk_f32_fp8(x0[u], true);
        a0.x = fmaf(s0[u], lo.x, a0.x);
        a0.y = fmaf(s0[u], lo.y, a0.y);
        a0.z = fmaf(s0[u], hi.x, a0.z);
        a0.w = fmaf(s0[u], hi.y, a0.w);
        lo = __builtin_amdgcn_cvt_pk_f32_fp8(x1[u], false);
        hi = __builtin_amdgcn_cvt_pk_f32_fp8(x1[u], true);
        a1.x = fmaf(s1[u], lo.x, a1.x);
        a1.y = fmaf(s1[u], lo.y, a1.y);
        a1.z = fmaf(s1[u], hi.x, a1.z);
        a1.w = fmaf(s1[u], hi.y, a1.w);
    }
}

// ---------------------------------------------------------------------------
// layer_fused: block = 16 rows (grid 625), 8 waves (512 thr).
// Phase 1: wave handles 2 rows interleaved; SOFTWARE-PIPELINED gather
//          (ping-pong A/B groups: group g+1's 16 loads issued before group g
//          is consumed -> ~600cy L2/LLC latency hides under cvt/fma).
//          FMA order identical to the proven kernel (self first, groups asc).
// Phase 2: wave handles 2 col-tiles; out = relu(sup @ M), M pre-folded.
// LAST: out tile -> LDS fp32, in-block logits + log_softmax -> out.
// ---------------------------------------------------------------------------
template<bool LAST>
__global__ __launch_bounds__(512, 6) void layer_fused(const unsigned int* __restrict__ h8,
                                                      const unsigned short* __restrict__ h0b,
                                                      const float* __restrict__ dinv,
                                                      const int* __restrict__ cnt,
                                                      const int2* __restrict__ es,
                                                      const unsigned short* __restrict__ Mt,
                                                      const float* __restrict__ w1,
                                                      const float* __restrict__ b1,
                                                      unsigned char* __restrict__ h8_out,
                                                      float* __restrict__ out) {
    __shared__ unsigned short supb[16][264];
    __shared__ float hs[LAST ? 16 * 264 : 4];

    int t = threadIdx.x;
    int wv = __builtin_amdgcn_readfirstlane(t >> 6);   // wave-uniform in SGPR
    int lane = t & 63;
    int r0 = blockIdx.x * 16;

    // ---- phase 1: pipelined fp8 gather + mix -> supb (LDS) ----
    int lr0 = wv * 2, lr1 = lr0 + 1;
    int i0 = r0 + lr0, i1 = r0 + lr1;

    // independent loads issued first (retire earliest; no pipeline impact)
    unsigned int su0 = h8[(size_t)i0 * 64 + lane];
    unsigned int su1 = h8[(size_t)i1 * 64 + lane];
    ushort4v h0v0 = ((const ushort4v*)h0b)[(size_t)i0 * 64 + lane];
    ushort4v h0v1 = ((const ushort4v*)h0b)[(size_t)i1 * 64 + lane];

    float di0 = dinv[i0], di1 = dinv[i1];
    int dA = (cnt[i0] + 7) & ~7, dB = (cnt[i1] + 7) & ~7;
    int dm = dA > dB ? dA : dB;                 // padded entries are x0.0
    const int2* e0r = es + (size_t)i0 * MAXDEG;
    const int2* e1r = es + (size_t)i1 * MAXDEG;

    // self term (identical order to proven kernel: acc init = di * self)
    floatx2 slo = __builtin_amdgcn_cvt_pk_f32_fp8(su0, false);
    floatx2 shi = __builtin_amdgcn_cvt_pk_f32_fp8(su0, true);
    float4 a0, a1;
    a0.x = di0 * slo.x; a0.y = di0 * slo.y; a0.z = di0 * shi.x; a0.w = di0 * shi.y;
    slo = __builtin_amdgcn_cvt_pk_f32_fp8(su1, false);
    shi = __builtin_amdgcn_cvt_pk_f32_fp8(su1, true);
    a1.x = di1 * slo.x; a1.y = di1 * slo.y; a1.z = di1 * shi.x; a1.w = di1 * shi.y;

    unsigned int xA0[8], xA1[8], xB0[8], xB1[8];
    float sA0[8], sA1[8], sB0[8], sB1[8];
    int ng = dm >> 3;                           // may be 0 (isolated row): safe
    load_group(e0r, e1r, h8, lane, 0, xA0, xA1, sA0, sA1);   // pads if ng==0
    bool useA = true;
    #pragma unroll 1
    for (int g = 1; g < ng; ++g) {
        if (useA) {
            load_group(e0r, e1r, h8, lane, g << 3, xB0, xB1, sB0, sB1);
            proc_group(xA0, xA1, sA0, sA1, a0, a1);
        } else {
            load_group(e0r, e1r, h8, lane, g << 3, xA0, xA1, sA0, sA1);
            proc_group(xB0, xB1, sB0, sB1, a0, a1);
        }
        useA = !useA;
    }
    if (useA) proc_group(xA0, xA1, sA0, sA1, a0, a1);
    else      proc_group(xB0, xB1, sB0, sB1, a0, a1);

    ushort4v ob;
    ob.x = f2bf(0.9f * (di0 * a0.x) + 0.1f * bf2f(h0v0.x));
    ob.y = f2bf(0.9f * (di0 * a0.y) + 0.1f * bf2f(h0v0.y));
    ob.z = f2bf(0.9f * (di0 * a0.z) + 0.1f * bf2f(h0v0.z));
    ob.w = f2bf(0.9f * (di0 * a0.w) + 0.1f * bf2f(h0v0.w));
    *(ushort4v*)&supb[lr0][4 * lane] = ob;
    ob.x = f2bf(0.9f * (di1 * a1.x) + 0.1f * bf2f(h0v1.x));
    ob.y = f2bf(0.9f * (di1 * a1.y) + 0.1f * bf2f(h0v1.y));
    ob.z = f2bf(0.9f * (di1 * a1.z) + 0.1f * bf2f(h0v1.z));
    ob.w = f2bf(0.9f * (di1 * a1.w) + 0.1f * bf2f(h0v1.w));
    *(ushort4v*)&supb[lr1][4 * lane] = ob;
    __syncthreads();

    // ---- phase 2: MFMA GEMM, epilogue = relu only (residual folded in M) ----
    int lrow = lane & 15, quad = lane >> 4;
    bf16x8 a[8];
    #pragma unroll
    for (int f = 0; f < 8; ++f)
        a[f] = *(const bf16x8*)&supb[lrow][quad * 8 + f * 32];

    #pragma unroll 1
    for (int n = 0; n < 2; ++n) {
        int nt = wv * 2 + n;
        floatx4 acc = {0.f, 0.f, 0.f, 0.f};
        const unsigned short* wrow = Mt + (size_t)(nt * 16 + lrow) * NHID + quad * 8;
        #pragma unroll
        for (int f = 0; f < 8; ++f) {
            bf16x8 b = *(const bf16x8*)(wrow + f * 32);
            acc = __builtin_amdgcn_mfma_f32_16x16x32_bf16(a[f], b, acc, 0, 0, 0);
        }
        int col = nt * 16 + lrow;
        #pragma unroll
        for (int r = 0; r < 4; ++r) {
            int lr2 = quad * 4 + r;
            float o = fmaxf(acc[r], 0.f);
            if (LAST) {
                hs[lr2 * 264 + col] = o;
            } else {
                h8_out[(size_t)(r0 + lr2) * NHID + col] = f2fp8(o);
            }
        }
    }

    // ---- phase 3 (LAST only): logits + log_softmax, in-block ----
    if (LAST) {
        __syncthreads();
        #pragma unroll 1
        for (int rr = 0; rr < 2; ++rr) {
            int lr = wv * 2 + rr;
            const float* hr = hs + lr * 264;
            float logit = -1e30f;
            if (lane < NCLASS) {
                float acc = b1[lane];
                #pragma unroll 8
                for (int k = 0; k < NHID; ++k)
                    acc = fmaf(hr[k], w1[k * NCLASS + lane], acc);
                logit = acc;
            }
            float m = logit;
            #pragma unroll
            for (int off = 32; off > 0; off >>= 1)
                m = fmaxf(m, __shfl_xor(m, off, 64));
            float e = (lane < NCLASS) ? expf(logit - m) : 0.0f;
            float ssum = e;
            #pragma unroll
            for (int off = 32; off > 0; off >>= 1)
                ssum += __shfl_xor(ssum, off, 64);
            float lse = m + logf(ssum);
            if (lane < NCLASS)
                out[(size_t)(r0 + lr) * NCLASS + lane] = logit - lse;
        }
    }
}

// ---------------------------------------------------------------------------
extern "C" void kernel_launch(void* const* d_in, const int* in_sizes, int n_in,
                              void* d_out, int out_size, void* d_ws, size_t ws_size,
                              hipStream_t stream) {
    const float* x      = (const float*)d_in[0];
    const float* adj    = (const float*)d_in[1];
    const float* w0     = (const float*)d_in[2];
    const float* b0     = (const float*)d_in[3];
    const float* conv_w = (const float*)d_in[4];
    const float* w1     = (const float*)d_in[5];
    const float* b1     = (const float*)d_in[6];
    float* out = (float*)d_out;

    char* ws = (char*)d_ws;
    size_t off = 0;
    auto alloc = [&](size_t bytes) -> void* {
        void* p = ws + off;
        off = (off + bytes + 255) & ~(size_t)255;
        return p;
    };
    float*          dinv  = (float*)alloc((size_t)NN * 4);
    int*            cnt   = (int*)  alloc((size_t)NN * 4);
    int*            ell   = (int*)  alloc((size_t)NN * MAXDEG * 4);
    int2*           es    = (int2*) alloc((size_t)NN * MAXDEG * 8);
    unsigned short* xb    = (unsigned short*)alloc((size_t)NN * NFEAT * 2);
    unsigned short* w0t   = (unsigned short*)alloc((size_t)NFEAT * NHID * 2);
    unsigned short* Mt    = (unsigned short*)alloc((size_t)NLAYERS * NHID * NHID * 2);
    unsigned short* h0b   = (unsigned short*)alloc((size_t)NN * NHID * 2);
    unsigned int*   h08   = (unsigned int*)alloc((size_t)NN * NHID);
    unsigned int*   hP8   = (unsigned int*)alloc((size_t)NN * NHID);
    unsigned int*   hQ8   = (unsigned int*)alloc((size_t)NN * NHID);

    build_graph<<<NN, 256, 0, stream>>>(adj, cnt, ell, dinv);
    convert_x<<<(NN * NFEAT / 4) / 256, 256, 0, stream>>>(x, xb);
    prep_weights<<<(131072 + NLAYERS * NHID * NHID) / 256, 256, 0, stream>>>(w0, conv_w, w0t, Mt);
    prep_ell<<<(NN * MAXDEG + 255) / 256, 256, 0, stream>>>(ell, cnt, dinv, es);
    gemm0_mfma<<<NN / 16, 512, 0, stream>>>(xb, w0t, b0, h0b, (unsigned char*)h08);

    const unsigned int* hc8 = h08;
    for (int l = 0; l < NLAYERS; ++l) {
        unsigned int* nxt = (l & 1) ? hQ8 : hP8;
        const unsigned short* wt = Mt + (size_t)l * NHID * NHID;
        if (l == NLAYERS - 1)
            layer_fused<true><<<NN / 16, 512, 0, stream>>>(hc8, h0b, dinv, cnt, es, wt, w1, b1, nullptr, out);
        else
            layer_fused<false><<<NN / 16, 512, 0, stream>>>(hc8, h0b, dinv, cnt, es, wt, nullptr, nullptr, (unsigned char*)nxt, nullptr);
        hc8 = nxt;
    }
}

// Round 7
// 777.674 us; speedup vs baseline: 4.0655x; 1.0956x over previous
//
#include <hip/hip_runtime.h>
#include <math.h>

#define NN 10000
#define NFEAT 512
#define NHID 256
#define NCLASS 40
#define NLAYERS 8
#define MAXDEG 96

#define CVX_BLOCKS 5000   // convert_x   : 1,280,000 float4 / 256
#define PW_BLOCKS  2560   // prep_weights:   655,360 idx   / 256
#define PE_BLOCKS  3750   // prep_ell    :   960,000 idx   / 256

typedef __attribute__((ext_vector_type(8))) short bf16x8;
typedef __attribute__((ext_vector_type(4))) float floatx4;
typedef __attribute__((ext_vector_type(2))) float floatx2;
typedef __attribute__((ext_vector_type(4))) unsigned short ushort4v;

__device__ __forceinline__ unsigned short f2bf(float f) {
    union { float f; unsigned int u; } v; v.f = f;
    unsigned int r = v.u + 0x7fffu + ((v.u >> 16) & 1u);  // RNE
    return (unsigned short)(r >> 16);
}
__device__ __forceinline__ float bf2f(unsigned short h) {
    union { unsigned int u; float f; } v; v.u = ((unsigned int)h) << 16;
    return v.f;
}
__device__ __forceinline__ unsigned char f2fp8(float f) {
    return (unsigned char)(__builtin_amdgcn_cvt_pk_fp8_f32(f, f, 0, false) & 0xFF);
}

// ---------------------------------------------------------------------------
// build_graph: one block per row; one pass over the 400MB dense adjacency.
// HBM-bound floor ~62us — irreducible.
// ---------------------------------------------------------------------------
__global__ __launch_bounds__(256) void build_graph(const float* __restrict__ adj,
                                                   int* __restrict__ cnt,
                                                   int* __restrict__ ell,
                                                   float* __restrict__ dinv) {
    int i = blockIdx.x;
    __shared__ int scnt;
    if (threadIdx.x == 0) scnt = 0;
    __syncthreads();
    const float4* row = (const float4*)(adj + (size_t)i * NN);
    const int nv = NN / 4;  // 2500
    int* erow = ell + (size_t)i * MAXDEG;
    for (int f = threadIdx.x; f < nv; f += 256) {
        float4 v = row[f];
        if (v.x != 0.0f) { int s = atomicAdd(&scnt, 1); if (s < MAXDEG) erow[s] = 4*f + 0; }
        if (v.y != 0.0f) { int s = atomicAdd(&scnt, 1); if (s < MAXDEG) erow[s] = 4*f + 1; }
        if (v.z != 0.0f) { int s = atomicAdd(&scnt, 1); if (s < MAXDEG) erow[s] = 4*f + 2; }
        if (v.w != 0.0f) { int s = atomicAdd(&scnt, 1); if (s < MAXDEG) erow[s] = 4*f + 3; }
    }
    __syncthreads();
    if (threadIdx.x == 0) {
        int c = scnt;
        cnt[i] = (c < MAXDEG) ? c : MAXDEG;
        dinv[i] = rsqrtf(1.0f + (float)c);
    }
}

// ---------------------------------------------------------------------------
// prep_all: convert_x + prep_weights + prep_ell merged (blockIdx-range split;
// the three are mutually independent, all only need build_graph's outputs).
//   [0, CVX)            : xb = bf16(x)
//   [CVX, CVX+PW)       : w0t/Mt transposes + residual fold
//   [CVX+PW, +PE)       : es[i][e] = (j, bits(dinv[j])) | (0, 0.0) pad
// ---------------------------------------------------------------------------
__global__ __launch_bounds__(256) void prep_all(const float* __restrict__ x,
                                                unsigned short* __restrict__ xb,
                                                const float* __restrict__ w0,
                                                const float* __restrict__ cw,
                                                unsigned short* __restrict__ w0t,
                                                unsigned short* __restrict__ Mt,
                                                const int* __restrict__ ell,
                                                const int* __restrict__ cnt,
                                                const float* __restrict__ dinv,
                                                int2* __restrict__ es) {
    int b = blockIdx.x, t = threadIdx.x;
    if (b < CVX_BLOCKS) {
        int idx = b * 256 + t;
        float4 v = ((const float4*)x)[idx];
        ushort4v o;
        o.x = f2bf(v.x); o.y = f2bf(v.y); o.z = f2bf(v.z); o.w = f2bf(v.w);
        ((ushort4v*)xb)[idx] = o;
    } else if (b < CVX_BLOCKS + PW_BLOCKS) {
        int idx = (b - CVX_BLOCKS) * 256 + t;
        if (idx < 131072) {
            int n = idx >> 9, k = idx & 511;
            w0t[idx] = f2bf(w0[(size_t)k * 256 + n]);
        } else {
            int j = idx - 131072;
            int l = j >> 16;
            int r = j & 65535;
            int n = r >> 8, k = r & 255;
            float theta = logf(0.5f / (float)(l + 1) + 1.0f);
            float v = theta * cw[(size_t)l * 65536 + (size_t)k * 256 + n];
            if (k == n) v += 1.0f - theta;
            Mt[j] = f2bf(v);
        }
    } else {
        int idx = (b - CVX_BLOCKS - PW_BLOCKS) * 256 + t;   // < 960000
        if (idx >= NN * MAXDEG) return;
        int i = idx / MAXDEG, e = idx % MAXDEG;
        int2 v; v.x = 0; v.y = 0;                            // pad: row 0, x0.0
        if (e < cnt[i]) {
            int j = ell[idx];
            v.x = j; v.y = __float_as_int(dinv[j]);
        }
        es[idx] = v;
    }
}

// ---------------------------------------------------------------------------
// gemm0: h0 = relu(x @ w0 + b0); writes bf16 h0b AND fp8 h08 (convert fused,
// numerically identical: fp8 encoded from the rounded bf16 value).
// ---------------------------------------------------------------------------
__global__ __launch_bounds__(512, 4) void gemm0_mfma(const unsigned short* __restrict__ xb,
                                                     const unsigned short* __restrict__ w0t,
                                                     const float* __restrict__ b0,
                                                     unsigned short* __restrict__ h0b,
                                                     unsigned char* __restrict__ h8o) {
    int t = threadIdx.x, wv = t >> 6, lane = t & 63;
    int lrow = lane & 15, quad = lane >> 4;
    int r0 = blockIdx.x * 16;

    bf16x8 a[16];
    const unsigned short* arow = xb + (size_t)(r0 + lrow) * NFEAT + quad * 8;
    #pragma unroll
    for (int f = 0; f < 16; ++f)
        a[f] = *(const bf16x8*)(arow + f * 32);

    #pragma unroll 1
    for (int n = 0; n < 2; ++n) {
        int nt = wv * 2 + n;
        floatx4 acc = {0.f, 0.f, 0.f, 0.f};
        const unsigned short* wrow = w0t + (size_t)(nt * 16 + lrow) * NFEAT + quad * 8;
        #pragma unroll
        for (int f = 0; f < 16; ++f) {
            bf16x8 b = *(const bf16x8*)(wrow + f * 32);
            acc = __builtin_amdgcn_mfma_f32_16x16x32_bf16(a[f], b, acc, 0, 0, 0);
        }
        int col = nt * 16 + lrow;
        float bias = b0[col];
        #pragma unroll
        for (int r = 0; r < 4; ++r) {
            int row = r0 + quad * 4 + r;
            unsigned short bv = f2bf(fmaxf(acc[r] + bias, 0.f));
            h0b[(size_t)row * NHID + col] = bv;
            h8o[(size_t)row * NHID + col] = f2fp8(bf2f(bv));
        }
    }
}

// ---------------------------------------------------------------------------
// gather pipeline helpers — HALF-GROUP (4 edges x 2 rows = 8 loads) so the
// ping-pong staging is 32 VGPRs total (R5's full-group version was 64 and
// spilled under the (512,6) cap of 85 -> scratch round-trips -> regression).
// ---------------------------------------------------------------------------
__device__ __forceinline__ void load_hg(const int2* __restrict__ e0r,
                                        const int2* __restrict__ e1r,
                                        const unsigned int* __restrict__ h8,
                                        int lane, int base,
                                        unsigned int (&x0)[4], unsigned int (&x1)[4],
                                        float (&s0)[4], float (&s1)[4]) {
    #pragma unroll
    for (int u = 0; u < 4; ++u) {
        int2 p = e0r[base + u];            // uniform -> s_load_dwordx2
        int2 q = e1r[base + u];
        s0[u] = __int_as_float(p.y);
        s1[u] = __int_as_float(q.y);
        x0[u] = h8[(size_t)p.x * 64 + lane];
        x1[u] = h8[(size_t)q.x * 64 + lane];
    }
}

__device__ __forceinline__ void proc_hg(const unsigned int (&x0)[4],
                                        const unsigned int (&x1)[4],
                                        const float (&s0)[4], const float (&s1)[4],
                                        float4& a0, float4& a1) {
    #pragma unroll
    for (int u = 0; u < 4; ++u) {
        floatx2 lo = __builtin_amdgcn_cvt_pk_f32_fp8(x0[u], false);
        floatx2 hi = __builtin_amdgcn_cvt_pk_f32_fp8(x0[u], true);
        a0.x = fmaf(s0[u], lo.x, a0.x);
        a0.y = fmaf(s0[u], lo.y, a0.y);
        a0.z = fmaf(s0[u], hi.x, a0.z);
        a0.w = fmaf(s0[u], hi.y, a0.w);
        lo = __builtin_amdgcn_cvt_pk_f32_fp8(x1[u], false);
        hi = __builtin_amdgcn_cvt_pk_f32_fp8(x1[u], true);
        a1.x = fmaf(s1[u], lo.x, a1.x);
        a1.y = fmaf(s1[u], lo.y, a1.y);
        a1.z = fmaf(s1[u], hi.x, a1.z);
        a1.w = fmaf(s1[u], hi.y, a1.w);
    }
}

// ---------------------------------------------------------------------------
// layer_fused: block = 16 rows (grid 625), 8 waves (512 thr).
// Phase 1: wave handles 2 rows interleaved; ping-pong pipelined gather at
//          half-group (4-edge) granularity: next 8 loads issued while current
//          8 are consumed -> L2/LLC latency exposed once per row-pair.
//          FMA order per accumulator identical to the proven kernel.
// Phase 2: wave handles 2 col-tiles; out = relu(sup @ M), M pre-folded.
// LAST: out tile -> LDS fp32, in-block logits + log_softmax -> out.
// ---------------------------------------------------------------------------
template<bool LAST>
__global__ __launch_bounds__(512, 6) void layer_fused(const unsigned int* __restrict__ h8,
                                                      const unsigned short* __restrict__ h0b,
                                                      const float* __restrict__ dinv,
                                                      const int* __restrict__ cnt,
                                                      const int2* __restrict__ es,
                                                      const unsigned short* __restrict__ Mt,
                                                      const float* __restrict__ w1,
                                                      const float* __restrict__ b1,
                                                      unsigned char* __restrict__ h8_out,
                                                      float* __restrict__ out) {
    __shared__ unsigned short supb[16][264];
    __shared__ float hs[LAST ? 16 * 264 : 4];

    int t = threadIdx.x;
    int wv = __builtin_amdgcn_readfirstlane(t >> 6);   // wave-uniform in SGPR
    int lane = t & 63;
    int r0 = blockIdx.x * 16;

    // ---- phase 1: pipelined fp8 gather + mix -> supb (LDS) ----
    int lr0 = wv * 2, lr1 = lr0 + 1;
    int i0 = r0 + lr0, i1 = r0 + lr1;

    // independent loads issued first (retire earliest; no pipeline impact)
    unsigned int su0 = h8[(size_t)i0 * 64 + lane];
    unsigned int su1 = h8[(size_t)i1 * 64 + lane];
    ushort4v h0v0 = ((const ushort4v*)h0b)[(size_t)i0 * 64 + lane];
    ushort4v h0v1 = ((const ushort4v*)h0b)[(size_t)i1 * 64 + lane];

    float di0 = dinv[i0], di1 = dinv[i1];
    int dA = (cnt[i0] + 7) & ~7, dB = (cnt[i1] + 7) & ~7;
    int dm = dA > dB ? dA : dB;                 // padded entries are x0.0
    const int2* e0r = es + (size_t)i0 * MAXDEG;
    const int2* e1r = es + (size_t)i1 * MAXDEG;

    // self term (identical order to proven kernel: acc init = di * self)
    floatx2 slo = __builtin_amdgcn_cvt_pk_f32_fp8(su0, false);
    floatx2 shi = __builtin_amdgcn_cvt_pk_f32_fp8(su0, true);
    float4 a0, a1;
    a0.x = di0 * slo.x; a0.y = di0 * slo.y; a0.z = di0 * shi.x; a0.w = di0 * shi.y;
    slo = __builtin_amdgcn_cvt_pk_f32_fp8(su1, false);
    shi = __builtin_amdgcn_cvt_pk_f32_fp8(su1, true);
    a1.x = di1 * slo.x; a1.y = di1 * slo.y; a1.z = di1 * shi.x; a1.w = di1 * shi.y;

    unsigned int xA0[4], xA1[4], xB0[4], xB1[4];
    float sA0[4], sA1[4], sB0[4], sB1[4];
    int nh = dm >> 2;                           // half-groups; even; 0 if isolated
    if (nh > 0) {
        load_hg(e0r, e1r, h8, lane, 0, xA0, xA1, sA0, sA1);
        bool useA = true;
        #pragma unroll 1
        for (int g = 1; g < nh; ++g) {
            if (useA) {
                load_hg(e0r, e1r, h8, lane, g << 2, xB0, xB1, sB0, sB1);
                proc_hg(xA0, xA1, sA0, sA1, a0, a1);
            } else {
                load_hg(e0r, e1r, h8, lane, g << 2, xA0, xA1, sA0, sA1);
                proc_hg(xB0, xB1, sB0, sB1, a0, a1);
            }
            useA = !useA;
        }
        if (useA) proc_hg(xA0, xA1, sA0, sA1, a0, a1);
        else      proc_hg(xB0, xB1, sB0, sB1, a0, a1);
    }

    ushort4v ob;
    ob.x = f2bf(0.9f * (di0 * a0.x) + 0.1f * bf2f(h0v0.x));
    ob.y = f2bf(0.9f * (di0 * a0.y) + 0.1f * bf2f(h0v0.y));
    ob.z = f2bf(0.9f * (di0 * a0.z) + 0.1f * bf2f(h0v0.z));
    ob.w = f2bf(0.9f * (di0 * a0.w) + 0.1f * bf2f(h0v0.w));
    *(ushort4v*)&supb[lr0][4 * lane] = ob;
    ob.x = f2bf(0.9f * (di1 * a1.x) + 0.1f * bf2f(h0v1.x));
    ob.y = f2bf(0.9f * (di1 * a1.y) + 0.1f * bf2f(h0v1.y));
    ob.z = f2bf(0.9f * (di1 * a1.z) + 0.1f * bf2f(h0v1.z));
    ob.w = f2bf(0.9f * (di1 * a1.w) + 0.1f * bf2f(h0v1.w));
    *(ushort4v*)&supb[lr1][4 * lane] = ob;
    __syncthreads();

    // ---- phase 2: MFMA GEMM, epilogue = relu only (residual folded in M) ----
    int lrow = lane & 15, quad = lane >> 4;
    bf16x8 a[8];
    #pragma unroll
    for (int f = 0; f < 8; ++f)
        a[f] = *(const bf16x8*)&supb[lrow][quad * 8 + f * 32];

    #pragma unroll 1
    for (int n = 0; n < 2; ++n) {
        int nt = wv * 2 + n;
        floatx4 acc = {0.f, 0.f, 0.f, 0.f};
        const unsigned short* wrow = Mt + (size_t)(nt * 16 + lrow) * NHID + quad * 8;
        #pragma unroll
        for (int f = 0; f < 8; ++f) {
            bf16x8 b = *(const bf16x8*)(wrow + f * 32);
            acc = __builtin_amdgcn_mfma_f32_16x16x32_bf16(a[f], b, acc, 0, 0, 0);
        }
        int col = nt * 16 + lrow;
        #pragma unroll
        for (int r = 0; r < 4; ++r) {
            int lr2 = quad * 4 + r;
            float o = fmaxf(acc[r], 0.f);
            if (LAST) {
                hs[lr2 * 264 + col] = o;
            } else {
                h8_out[(size_t)(r0 + lr2) * NHID + col] = f2fp8(o);
            }
        }
    }

    // ---- phase 3 (LAST only): logits + log_softmax, in-block ----
    if (LAST) {
        __syncthreads();
        #pragma unroll 1
        for (int rr = 0; rr < 2; ++rr) {
            int lr = wv * 2 + rr;
            const float* hr = hs + lr * 264;
            float logit = -1e30f;
            if (lane < NCLASS) {
                float acc = b1[lane];
                #pragma unroll 8
                for (int k = 0; k < NHID; ++k)
                    acc = fmaf(hr[k], w1[k * NCLASS + lane], acc);
                logit = acc;
            }
            float m = logit;
            #pragma unroll
            for (int off = 32; off > 0; off >>= 1)
                m = fmaxf(m, __shfl_xor(m, off, 64));
            float e = (lane < NCLASS) ? expf(logit - m) : 0.0f;
            float ssum = e;
            #pragma unroll
            for (int off = 32; off > 0; off >>= 1)
                ssum += __shfl_xor(ssum, off, 64);
            float lse = m + logf(ssum);
            if (lane < NCLASS)
                out[(size_t)(r0 + lr) * NCLASS + lane] = logit - lse;
        }
    }
}

// ---------------------------------------------------------------------------
extern "C" void kernel_launch(void* const* d_in, const int* in_sizes, int n_in,
                              void* d_out, int out_size, void* d_ws, size_t ws_size,
                              hipStream_t stream) {
    const float* x      = (const float*)d_in[0];
    const float* adj    = (const float*)d_in[1];
    const float* w0     = (const float*)d_in[2];
    const float* b0     = (const float*)d_in[3];
    const float* conv_w = (const float*)d_in[4];
    const float* w1     = (const float*)d_in[5];
    const float* b1     = (const float*)d_in[6];
    float* out = (float*)d_out;

    char* ws = (char*)d_ws;
    size_t off = 0;
    auto alloc = [&](size_t bytes) -> void* {
        void* p = ws + off;
        off = (off + bytes + 255) & ~(size_t)255;
        return p;
    };
    float*          dinv  = (float*)alloc((size_t)NN * 4);
    int*            cnt   = (int*)  alloc((size_t)NN * 4);
    int*            ell   = (int*)  alloc((size_t)NN * MAXDEG * 4);
    int2*           es    = (int2*) alloc((size_t)NN * MAXDEG * 8);
    unsigned short* xb    = (unsigned short*)alloc((size_t)NN * NFEAT * 2);
    unsigned short* w0t   = (unsigned short*)alloc((size_t)NFEAT * NHID * 2);
    unsigned short* Mt    = (unsigned short*)alloc((size_t)NLAYERS * NHID * NHID * 2);
    unsigned short* h0b   = (unsigned short*)alloc((size_t)NN * NHID * 2);
    unsigned int*   h08   = (unsigned int*)alloc((size_t)NN * NHID);
    unsigned int*   hP8   = (unsigned int*)alloc((size_t)NN * NHID);
    unsigned int*   hQ8   = (unsigned int*)alloc((size_t)NN * NHID);

    build_graph<<<NN, 256, 0, stream>>>(adj, cnt, ell, dinv);
    prep_all<<<CVX_BLOCKS + PW_BLOCKS + PE_BLOCKS, 256, 0, stream>>>(
        x, xb, w0, conv_w, w0t, Mt, ell, cnt, dinv, es);
    gemm0_mfma<<<NN / 16, 512, 0, stream>>>(xb, w0t, b0, h0b, (unsigned char*)h08);

    const unsigned int* hc8 = h08;
    for (int l = 0; l < NLAYERS; ++l) {
        unsigned int* nxt = (l & 1) ? hQ8 : hP8;
        const unsigned short* wt = Mt + (size_t)l * NHID * NHID;
        if (l == NLAYERS - 1)
            layer_fused<true><<<NN / 16, 512, 0, stream>>>(hc8, h0b, dinv, cnt, es, wt, w1, b1, nullptr, out);
        else
            layer_fused<false><<<NN / 16, 512, 0, stream>>>(hc8, h0b, dinv, cnt, es, wt, nullptr, nullptr, (unsigned char*)nxt, nullptr);
        hc8 = nxt;
    }
}